// Round 6
// baseline (841.826 us; speedup 1.0000x reference)
//
#include <hip/hip_runtime.h>

#define B_N   262144
#define D_IN  256
#define H_DIM 64

// ---- workspace layout (bytes) ----
//   [0,4)                      : dtype flag (sniff_kernel)
//   [16, 16+163840)            : bf16 weight cache (81920 elems)
//   [163856, 163856+3104)      : f32 bias cache (776 elems, 16B-aligned blocks)
#define WKS_BYTE_OFF 16
#define BKS_BYTE_OFF (WKS_BYTE_OFF + 81920 * 2)   // 163856 (16B aligned)
#define WS_NEEDED    (BKS_BYTE_OFF + 776 * 4)      // 166960

// bf16 weight cache element offsets (row-major mats)
#define WF1(s)  ((size_t)(s) * 16384)              // Wfc1 [64][256]
#define WIH(s)  (32768 + (size_t)(s) * 24576)      // wih  [192][64]
#define WHH(s)  (WIH(s) + 12288)                   // whh  [192][64]
// f32 bias cache per-stream block (stride 388 floats, 16B aligned):
//   +0 fc1(64) | +64 rz_sum(128: r then z, bih+bhh presummed)
//   +192 ih_n(64) | +256 hh_n(64) | +320 w2(64) | +384 b2
#define BB(s)   ((s) * 388)

typedef __attribute__((ext_vector_type(8))) short bf16x8;   // 8 bf16 = 4 VGPRs
typedef __attribute__((ext_vector_type(4))) float f32x4;    // MFMA 16x16 accumulator
typedef __attribute__((ext_vector_type(4))) unsigned int u32x4;
typedef __attribute__((ext_vector_type(2))) unsigned int u32x2;

__device__ __forceinline__ float b2f(unsigned short u) {
    union { unsigned int i; float f; } c; c.i = ((unsigned int)u) << 16; return c.f;
}
__device__ __forceinline__ unsigned short f2b(float f) {
    union { float f; unsigned int i; } c; c.f = f;
    unsigned int u = c.i;
    return (unsigned short)((u + 0x7FFFu + ((u >> 16) & 1u)) >> 16);
}
__device__ __forceinline__ unsigned int cvtpk(float lo, float hi) {
    unsigned int r;
    asm("v_cvt_pk_bf16_f32 %0, %1, %2" : "=v"(r) : "v"(lo), "v"(hi));
    return r;
}
__device__ __forceinline__ float sigm(float x)   { return 1.0f / (1.0f + __expf(-x)); }
__device__ __forceinline__ float tanh_f(float x) { return 1.0f - 2.0f / (__expf(2.0f * x) + 1.0f); }

__device__ __forceinline__ bf16x8 load8(const void* p, size_t i, bool f32) {
    if (f32) {
        const float* q = (const float*)p + i;
        float4 a = *(const float4*)q;
        float4 b = *(const float4*)(q + 4);
        union { u32x4 u; bf16x8 v; } c;
        c.u[0] = cvtpk(a.x, a.y); c.u[1] = cvtpk(a.z, a.w);
        c.u[2] = cvtpk(b.x, b.y); c.u[3] = cvtpk(b.z, b.w);
        return c.v;
    }
    return *(const bf16x8*)((const unsigned short*)p + i);
}
__device__ __forceinline__ float4 ld4(const void* p, size_t i, bool f32) {
    if (f32) return *(const float4*)((const float*)p + i);
    ushort4 u = *(const ushort4*)((const unsigned short*)p + i);
    return make_float4(b2f(u.x), b2f(u.y), b2f(u.z), b2f(u.w));
}
__device__ __forceinline__ float ld1(const void* p, size_t i, bool f32) {
    return f32 ? ((const float*)p)[i] : b2f(((const unsigned short*)p)[i]);
}
__device__ __forceinline__ void st1(void* p, size_t i, bool f32, float v) {
    if (f32) ((float*)p)[i] = v;
    else     ((unsigned short*)p)[i] = f2b(v);
}

// Sniff obs dtype: fp32 N(0,1) data viewed as ushorts has ~1/256 of (even-index)
// shorts with bf16-exponent 0xFF; genuine bf16 N(0,1) data has none.
__global__ void sniff_kernel(const unsigned short* __restrict__ obs, int* __restrict__ flag) {
    __shared__ int total;
    if (threadIdx.x == 0) total = 0;
    __syncthreads();
    int cnt = 0;
    for (int i = threadIdx.x; i < 16384; i += 256) {
        int e = (obs[i] >> 7) & 0xFF;
        cnt += (e == 0xFF) ? 1 : 0;
    }
    atomicAdd(&total, cnt);
    __syncthreads();
    if (threadIdx.x == 0) *flag = (total > 4) ? 1 : 0;   // 1 = fp32 buffers
}

// One-shot cache build: weights -> bf16 row-major; biases -> f32 (rz presummed,
// 16B-aligned per-stream blocks so the main kernel uses float4 bias loads).
__global__ void convert_weights_kernel(
    const void* Wfc1_1, const void* wih_1, const void* whh_1, const void* Wfc2_1,
    const void* bfc1_1, const void* bih_1, const void* bhh_1, const void* bfc2_1,
    const void* Wfc1_2, const void* wih_2, const void* whh_2, const void* Wfc2_2,
    const void* bfc1_2, const void* bih_2, const void* bhh_2, const void* bfc2_2,
    const int* __restrict__ flag,
    unsigned short* __restrict__ wks, float* __restrict__ bks)
{
    const bool f32 = (*flag != 0);
    const void*  wsrc[6] = {Wfc1_1, wih_1, whh_1, Wfc1_2, wih_2, whh_2};
    const int    wcnt[6] = {16384, 12288, 12288, 16384, 12288, 12288};
    const size_t woff[6] = {WF1(0), WIH(0), WHH(0), WF1(1), WIH(1), WHH(1)};
    const int tid = blockIdx.x * blockDim.x + threadIdx.x;
    const int nth = gridDim.x * blockDim.x;
    for (int m = 0; m < 6; ++m)
        for (int i = tid; i < wcnt[m]; i += nth)
            wks[woff[m] + i] = f32 ? f2b(((const float*)wsrc[m])[i])
                                   : ((const unsigned short*)wsrc[m])[i];
    const void* bfc1s[2] = {bfc1_1, bfc1_2};
    const void* bihs[2]  = {bih_1,  bih_2};
    const void* bhhs[2]  = {bhh_1,  bhh_2};
    const void* wfc2s[2] = {Wfc2_1, Wfc2_2};
    const void* bfc2s[2] = {bfc2_1, bfc2_2};
    for (int s = 0; s < 2; ++s) {
        float* d = &bks[BB(s)];
        for (int i = tid; i < 64; i += nth)  d[i]       = ld1(bfc1s[s], i, f32);
        for (int i = tid; i < 128; i += nth) d[64 + i]  = ld1(bihs[s], i, f32) + ld1(bhhs[s], i, f32);
        for (int i = tid; i < 64; i += nth)  d[192 + i] = ld1(bihs[s], 128 + i, f32);
        for (int i = tid; i < 64; i += nth)  d[256 + i] = ld1(bhhs[s], 128 + i, f32);
        for (int i = tid; i < 64; i += nth)  d[320 + i] = ld1(wfc2s[s], i, f32);
        if (tid == 0) d[384] = ld1(bfc2s[s], 0, f32);
    }
}

// Main kernel, swapped-operand formulation: batch is LANE-LOCAL everywhere.
//   Phase 1 (per rowblock rb): D = Wfc1 x obs^T via mfma(A=Wfc1row, B=obsrow)
//     -> lane (lm,lq) holds x[b=rb*16+lm][hcol=n*16+lq*4+r]. Packed to bf16 and
//     written to a swizzled per-wave LDS tile [32][64] (write b64 own-row,
//     read b128; byte ^= (row&7)<<4 kills the stride-128B bank conflict).
//   Phase 2: gates^T = mfma(A=Wrow, B=x/h frags); r,z accumulate ih+hh into ONE
//     acc each (C-in chaining). Epilogue is lane-local in batch: hv = one
//     float4/j, mask = 1 load/m2, new_h = full-line float4 stores, value head =
//     per-lane dot + 2 shfl_xor.
// Occupancy: LDS 32KB/block (5 blocks/CU) + waves_per_eu(5) (102-reg budget)
// -> ~20 waves/CU vs r5's 16. All LDS wave-private -> no barriers.
__global__ __launch_bounds__(256) __attribute__((amdgpu_waves_per_eu(5)))
void gru_critic_kernel(
    const void* __restrict__ obs,
    const void* __restrict__ h1,
    const void* __restrict__ h2,
    const int*  __restrict__ mask,
    const unsigned short* __restrict__ wks, const float* __restrict__ bks,
    const int*  __restrict__ flag,
    void* __restrict__ out)
{
    __shared__ __align__(16) unsigned short lds[4 * 4096];   // 32,768 B: per-wave 2 streams x [32][64]

    const bool f32 = (*flag != 0);
    const int lane = threadIdx.x & 63;
    const int wave = threadIdx.x >> 6;
    const int lm   = lane & 15;
    const int lq   = lane >> 4;
    const int row0 = blockIdx.x * 128 + wave * 32;
    char* xb0 = (char*)&lds[wave * 4096];   // + s*4096 bytes per stream

    // ---------- Phase 1: x_s^T = Wfc1_s x obs^T, two rowblock passes ----------
    for (int rb = 0; rb < 2; ++rb) {
        f32x4 acc[2][4];
        #pragma unroll
        for (int s2 = 0; s2 < 2; ++s2)
            #pragma unroll
            for (int n = 0; n < 4; ++n)
                acc[s2][n] = (f32x4){0.f, 0.f, 0.f, 0.f};

        #pragma unroll
        for (int kc = 0; kc < 8; ++kc) {
            // B-operand: lane holds obs[b=row0+rb*16+lm][kc*32+lq*8 ..+7]
            bf16x8 bo = load8(obs, (size_t)(row0 + rb * 16 + lm) * D_IN + kc * 32 + lq * 8, f32);
            #pragma unroll
            for (int n = 0; n < 4; ++n) {
                const size_t wi = (size_t)(n * 16 + lm) * D_IN + kc * 32 + lq * 8;
                bf16x8 w0 = *(const bf16x8*)&wks[WF1(0) + wi];   // A: Wfc1 row n*16+lm
                bf16x8 w1 = *(const bf16x8*)&wks[WF1(1) + wi];
                acc[0][n] = __builtin_amdgcn_mfma_f32_16x16x32_bf16(w0, bo, acc[0][n], 0, 0, 0);
                acc[1][n] = __builtin_amdgcn_mfma_f32_16x16x32_bf16(w1, bo, acc[1][n], 0, 0, 0);
            }
        }
        // lane holds x[b=rb*16+lm][hcol=n*16+lq*4+r]; tanh+bias, pack, swizzled LDS
        const int row = rb * 16 + lm;
        const int sw  = (row & 7) << 4;
        #pragma unroll
        for (int s2 = 0; s2 < 2; ++s2) {
            #pragma unroll
            for (int n = 0; n < 4; ++n) {
                float4 bi = *(const float4*)&bks[BB(s2) + n * 16 + lq * 4];
                float t0 = tanh_f(acc[s2][n][0] + bi.x);
                float t1 = tanh_f(acc[s2][n][1] + bi.y);
                float t2 = tanh_f(acc[s2][n][2] + bi.z);
                float t3 = tanh_f(acc[s2][n][3] + bi.w);
                u32x2 p; p[0] = cvtpk(t0, t1); p[1] = cvtpk(t2, t3);
                *(u32x2*)(xb0 + s2 * 4096 + ((row * 128 + n * 32 + lq * 8) ^ sw)) = p;
            }
        }
    }
    // no barrier: tiles are wave-private; compiler orders LDS via lgkmcnt

    // ---------- Phase 2: GRU gates (gates^T), new_h, value head ----------
    for (int s = 0; s < 2; ++s) {
        const void* h = s ? h2 : h1;
        const unsigned short* wih = &wks[WIH(s)];
        const unsigned short* whh = &wks[WHH(s)];
        const float* bb = &bks[BB(s)];
        const float b2v = bb[384];
        char* xb = xb0 + s * 4096;

        for (int m2 = 0; m2 < 2; ++m2) {
            const int b   = row0 + m2 * 16 + lm;     // lane's batch row
            const int row = m2 * 16 + lm;
            const int sw  = (row & 7) << 4;
            const int mk  = mask[b];

            bf16x8 ax[2], ah[2];
            #pragma unroll
            for (int kk = 0; kk < 2; ++kk) {
                ax[kk] = *(const bf16x8*)(xb + ((row * 128 + kk * 64 + lq * 16) ^ sw));
                ah[kk] = load8(h, (size_t)b * H_DIM + kk * 32 + lq * 8, f32);
            }

            float vp = 0.f;
            for (int j = 0; j < 4; ++j) {   // 16-row gate block (rolled: bounds pressure)
                // early: hv for this j (lane-local row, 16B) — hides under MFMAs
                float4 hx = ld4(h, (size_t)b * H_DIM + j * 16 + lq * 4, f32);
                const size_t ro = (size_t)(j * 16 + lm) * H_DIM + lq * 8;
                f32x4 a_r = {0,0,0,0}, a_z = {0,0,0,0}, a_in = {0,0,0,0}, a_hn = {0,0,0,0};
                #pragma unroll
                for (int kk = 0; kk < 2; ++kk) {
                    const size_t o = ro + kk * 32;
                    a_r  = __builtin_amdgcn_mfma_f32_16x16x32_bf16(*(const bf16x8*)&wih[o],            ax[kk], a_r,  0, 0, 0);
                    a_z  = __builtin_amdgcn_mfma_f32_16x16x32_bf16(*(const bf16x8*)&wih[64*64 + o],    ax[kk], a_z,  0, 0, 0);
                    a_in = __builtin_amdgcn_mfma_f32_16x16x32_bf16(*(const bf16x8*)&wih[128*64 + o],   ax[kk], a_in, 0, 0, 0);
                    a_r  = __builtin_amdgcn_mfma_f32_16x16x32_bf16(*(const bf16x8*)&whh[o],            ah[kk], a_r,  0, 0, 0);
                    a_z  = __builtin_amdgcn_mfma_f32_16x16x32_bf16(*(const bf16x8*)&whh[64*64 + o],    ah[kk], a_z,  0, 0, 0);
                    a_hn = __builtin_amdgcn_mfma_f32_16x16x32_bf16(*(const bf16x8*)&whh[128*64 + o],   ah[kk], a_hn, 0, 0, 0);
                }
                const int g4 = j * 16 + lq * 4;      // lane's 4 gate columns
                float4 br4  = *(const float4*)&bb[64 + g4];
                float4 bz4  = *(const float4*)&bb[128 + g4];
                float4 bin4 = *(const float4*)&bb[192 + g4];
                float4 bhn4 = *(const float4*)&bb[256 + g4];
                float4 w24  = *(const float4*)&bb[320 + g4];
                float nh[4];
                #pragma unroll
                for (int r = 0; r < 4; ++r) {
                    const float hvv = ((const float*)&hx)[r];
                    const float rg = sigm(a_r[r] + ((const float*)&br4)[r]);
                    const float zg = sigm(a_z[r] + ((const float*)&bz4)[r]);
                    const float ng = tanh_f(a_in[r] + ((const float*)&bin4)[r]
                                            + rg * (a_hn[r] + ((const float*)&bhn4)[r]));
                    nh[r] = mk ? ((1.0f - zg) * ng + zg * hvv) : hvv;
                    vp += nh[r] * ((const float*)&w24)[r];
                }
                // new_h store: 4 lanes (lq 0..3) of same lm cover one 64B line
                const size_t ho = 2 * (size_t)B_N + (size_t)s * B_N * H_DIM
                                + (size_t)b * H_DIM + g4;
                if (f32) {
                    float4 o4 = {nh[0], nh[1], nh[2], nh[3]};
                    *(float4*)((float*)out + ho) = o4;
                } else {
                    u32x2 o2; o2[0] = cvtpk(nh[0], nh[1]); o2[1] = cvtpk(nh[2], nh[3]);
                    *(u32x2*)((unsigned short*)out + ho) = o2;
                }
            }
            // value head: sum over lq quads only (batch is lane-local)
            vp += __shfl_xor(vp, 16);
            vp += __shfl_xor(vp, 32);
            if (lq == 0)
                st1(out, (size_t)s * B_N + b, f32, vp + b2v);
        }
    }
}

// Correctness-only fallback if workspace is too small (never expected to run).
__global__ void gru_critic_naive(
    const void* __restrict__ obs, const void* __restrict__ h1, const void* __restrict__ h2,
    const int* __restrict__ mask,
    const void* __restrict__ Wfc1_1, const void* __restrict__ bfc1_1,
    const void* __restrict__ wih_1,  const void* __restrict__ whh_1,
    const void* __restrict__ bih_1,  const void* __restrict__ bhh_1,
    const void* __restrict__ Wfc2_1, const void* __restrict__ bfc2_1,
    const void* __restrict__ Wfc1_2, const void* __restrict__ bfc1_2,
    const void* __restrict__ wih_2,  const void* __restrict__ whh_2,
    const void* __restrict__ bih_2,  const void* __restrict__ bhh_2,
    const void* __restrict__ Wfc2_2, const void* __restrict__ bfc2_2,
    const int* __restrict__ flag, void* __restrict__ out)
{
    const int b = blockIdx.x * blockDim.x + threadIdx.x;
    if (b >= B_N) return;
    const bool f32 = (*flag != 0);
    const int mk = mask[b];
    const void* Wf1[2] = {Wfc1_1, Wfc1_2}; const void* bf1[2] = {bfc1_1, bfc1_2};
    const void* wi[2]  = {wih_1, wih_2};   const void* wh[2]  = {whh_1, whh_2};
    const void* bi[2]  = {bih_1, bih_2};   const void* bh[2]  = {bhh_1, bhh_2};
    const void* W2[2]  = {Wfc2_1, Wfc2_2}; const void* b2[2]  = {bfc2_1, bfc2_2};
    const void* hs[2]  = {h1, h2};
    for (int s = 0; s < 2; ++s) {
        float x[H_DIM];
        for (int c = 0; c < H_DIM; ++c) {
            float sum = ld1(bf1[s], c, f32);
            for (int k = 0; k < D_IN; ++k)
                sum += ld1(obs, (size_t)b * D_IN + k, f32) * ld1(Wf1[s], (size_t)c * D_IN + k, f32);
            x[c] = tanh_f(sum);
        }
        float v = ld1(b2[s], 0, f32);
        for (int g = 0; g < H_DIM; ++g) {
            float ir = ld1(bi[s], g, f32), iz = ld1(bi[s], 64 + g, f32), in_ = ld1(bi[s], 128 + g, f32);
            float hr = ld1(bh[s], g, f32), hz = ld1(bh[s], 64 + g, f32), hn_ = ld1(bh[s], 128 + g, f32);
            for (int k = 0; k < H_DIM; ++k) {
                const float xk = x[k], hk = ld1(hs[s], (size_t)b * H_DIM + k, f32);
                ir += xk * ld1(wi[s], (size_t)g * H_DIM + k, f32);
                iz += xk * ld1(wi[s], (size_t)(64 + g) * H_DIM + k, f32);
                in_ += xk * ld1(wi[s], (size_t)(128 + g) * H_DIM + k, f32);
                hr += hk * ld1(wh[s], (size_t)g * H_DIM + k, f32);
                hz += hk * ld1(wh[s], (size_t)(64 + g) * H_DIM + k, f32);
                hn_ += hk * ld1(wh[s], (size_t)(128 + g) * H_DIM + k, f32);
            }
            const float hv = ld1(hs[s], (size_t)b * H_DIM + g, f32);
            const float rg = sigm(ir + hr), zg = sigm(iz + hz);
            const float ng = tanh_f(in_ + rg * hn_);
            const float nh = mk ? ((1.0f - zg) * ng + zg * hv) : hv;
            st1(out, 2 * (size_t)B_N + (size_t)s * B_N * H_DIM + (size_t)b * H_DIM + g, f32, nh);
            v += nh * ld1(W2[s], g, f32);
        }
        st1(out, (size_t)s * B_N + b, f32, v);
    }
}

extern "C" void kernel_launch(void* const* d_in, const int* in_sizes, int n_in,
                              void* d_out, int out_size, void* d_ws, size_t ws_size,
                              hipStream_t stream) {
    int* flag = (int*)d_ws;
    hipLaunchKernelGGL(sniff_kernel, dim3(1), dim3(256), 0, stream,
                       (const unsigned short*)d_in[0], flag);

    if (ws_size >= (size_t)WS_NEEDED) {
        unsigned short* wks = (unsigned short*)((char*)d_ws + WKS_BYTE_OFF);
        float*          bks = (float*)((char*)d_ws + BKS_BYTE_OFF);
        hipLaunchKernelGGL(convert_weights_kernel, dim3(64), dim3(256), 0, stream,
            d_in[4],  d_in[6],  d_in[7],  d_in[10],   // W_fc1_1, w_ih_1, w_hh_1, W_fc2_1
            d_in[5],  d_in[8],  d_in[9],  d_in[11],   // b_fc1_1, b_ih_1, b_hh_1, b_fc2_1
            d_in[12], d_in[14], d_in[15], d_in[18],   // W_fc1_2, w_ih_2, w_hh_2, W_fc2_2
            d_in[13], d_in[16], d_in[17], d_in[19],   // b_fc1_2, b_ih_2, b_hh_2, b_fc2_2
            flag, wks, bks);
        hipLaunchKernelGGL(gru_critic_kernel, dim3(B_N / 128), dim3(256), 0, stream,
            d_in[0], d_in[1], d_in[2], (const int*)d_in[3],
            wks, bks, flag, d_out);
    } else {
        hipLaunchKernelGGL(gru_critic_naive, dim3(B_N / 256), dim3(256), 0, stream,
            d_in[0], d_in[1], d_in[2], (const int*)d_in[3],
            d_in[4],  d_in[5],  d_in[6],  d_in[7],  d_in[8],  d_in[9],
            d_in[10], d_in[11],
            d_in[12], d_in[13], d_in[14], d_in[15], d_in[16], d_in[17],
            d_in[18], d_in[19],
            flag, d_out);
    }
}